// Round 6
// baseline (308.261 us; speedup 1.0000x reference)
//
#include <hip/hip_runtime.h>

#define N_NODE 200
#define T_LEN 360
#define T_POOL 350
#define P_PAT 400
#define P_PAD 512
#define NWIN 14
#define STRIDE_ 25
#define KPAD 224            // 7 stages x 32

// ---- workspace layout (bytes) ----
#define O_AH    0           // A hi, MFMA-fragment order: [7][8][4][64][8] bf16 = 229376
#define O_AL    229376
#define O_MG    458752      // [200][200] i32 = 160000 (memset 0)
#define O_CTR   618752      // [128] u32 (memset 0, same node)
#define O_POS   619264      // [128][512][14] f32 = 3670016 (owner-written, no zero needed)
#define O_TOPN  4289280
#define O_TOPV  4294080
#define O_NORMT 4298880

typedef unsigned short u16;
typedef __attribute__((ext_vector_type(8))) short bf16x8;
typedef __attribute__((ext_vector_type(4))) float f32x4;

// LDS layout (bytes) for the GEMM kernel
#define RP 2064             // X row pitch (4 k-oct rows; even-t [0,1024), odd-t [1024,2048))
#define XLOFF 8256          // lo-plane offset within a buffer
#define DBS 16512           // double-buffer stride
#define SQOFF 16896         // ssq scratch (aliases dead buf1 after k-loop)
#define IVOFF 18944         // inv-norm per local t (128 f32)
#define WMOFF 33024         // persistent window-max [128][14] f32 = 7168
#define SMEM_BYTES 40192

__device__ __forceinline__ u16 f2bf(float f) {          // RNE (A-side prep only)
    unsigned u = __float_as_uint(f);
    unsigned r = u + 0x7FFFu + ((u >> 16) & 1u);
    return (u16)(r >> 16);
}
__device__ __forceinline__ float bf2f(u16 h) { return __uint_as_float(((unsigned)h) << 16); }

// ---- pattern prep: normalize, top-3, norm term, maskgraph, frag-order bf16 split ----
__global__ void k_pat(const float* __restrict__ pat, u16* __restrict__ Ah, u16* __restrict__ Al,
                      int* __restrict__ mg, int* __restrict__ topn_w,
                      float* __restrict__ topv_w, float* __restrict__ normt)
{
    int p = blockIdx.x;               // 0..511
    int lane = threadIdx.x;
    bool pv = p < P_PAT;

    float sv[4], av[4];
    int nn[4];
    float ss = 0.f;
    #pragma unroll
    for (int j = 0; j < 4; ++j) {
        int n = lane + 64 * j;
        nn[j] = n;
        if (pv && n < N_NODE) { float v = pat[p * N_NODE + n]; sv[j] = v; av[j] = fabsf(v); ss += v * v; }
        else { sv[j] = 0.f; av[j] = -1.f; }
    }
    #pragma unroll
    for (int off = 32; off >= 1; off >>= 1) ss += __shfl_xor(ss, off);
    float rn = 1.0f / sqrtf(ss + 1e-9f);

    int pb = p >> 6, ii = (p >> 4) & 3, plm = p & 15;
    #pragma unroll
    for (int j = 0; j < 4; ++j) {
        int n = nn[j];
        if (n < KPAD) {
            float v = (pv && n < N_NODE) ? sv[j] * rn : 0.f;
            u16 h = f2bf(v);
            u16 l = f2bf(v - bf2f(h));
            int s = n >> 5, c = n & 31, quad = c >> 3, e = c & 7;
            size_t idx = ((size_t)((s * 8 + pb) * 4 + ii) * 64 + quad * 16 + plm) * 8 + e;
            Ah[idx] = h; Al[idx] = l;
        }
    }
    if (!pv) return;

    int topn[3]; float topv[3];
    for (int r = 0; r < 3; ++r) {
        float bv = -2.f; int bi = 1 << 30;
        #pragma unroll
        for (int j = 0; j < 4; ++j)
            if (av[j] > bv || (av[j] == bv && nn[j] < bi)) { bv = av[j]; bi = nn[j]; }
        #pragma unroll
        for (int off = 32; off >= 1; off >>= 1) {
            float ov = __shfl_xor(bv, off); int oi = __shfl_xor(bi, off);
            if (ov > bv || (ov == bv && oi < bi)) { bv = ov; bi = oi; }
        }
        int jj = bi >> 6, src = bi & 63;
        float rawj = (jj == 0) ? sv[0] : (jj == 1) ? sv[1] : (jj == 2) ? sv[2] : sv[3];
        float raw = __shfl(rawj, src);
        topn[r] = bi; topv[r] = raw * rn;
        #pragma unroll
        for (int j = 0; j < 4; ++j) if (nn[j] == bi) av[j] = -1.f;
    }
    float fullnorm = sqrtf(ss) * rn;
    float topnorm = sqrtf(topv[0]*topv[0] + topv[1]*topv[1] + topv[2]*topv[2]);
    if (lane == 0) {
        float d = 1.0f - topnorm / fullnorm;
        normt[p] = d * d * (1.0f / 800.0f);
    }
    if (lane < 3) { topn_w[p * 3 + lane] = topn[lane]; topv_w[p * 3 + lane] = topv[lane]; }
    if (lane < 9) {
        int i = lane / 3, j = lane % 3;
        atomicAdd(&mg[topn[i] * N_NODE + topn[j]], 1);
    }
}

// ---- fused: MFMA GEMM over 3 t-tiles (owner of (b,ptile)) + pooling + last-block classifier ----
__global__ __launch_bounds__(256, 2) void k_gemm(const float* __restrict__ x,
    const u16* __restrict__ AhF, const u16* __restrict__ AlF,
    const int* __restrict__ length, float* __restrict__ pos,
    unsigned* __restrict__ ctr,
    const int* __restrict__ topn_w, const float* __restrict__ topv_w,
    const int* __restrict__ mg, const float* __restrict__ W,
    const float* __restrict__ normt, const float* __restrict__ bcls,
    float* __restrict__ out)
{
    __shared__ __align__(16) char smem[SMEM_BYTES];
    int tid = threadIdx.x;
    int blk = blockIdx.x;
    // XCD co-location: the 4 ptiles of a b are congruent mod 8 -> same XCD
    int ptile = (blk >> 3) & 3;
    int b = (blk & 7) + 8 * (blk >> 5);
    int p0 = ptile * 128;
    int lane = tid & 63, wid = tid >> 6;
    int quad = lane >> 4, lm = lane & 15;
    int wp = wid >> 1, wt = wid & 1;
    int pbq = ptile * 2 + wp;
    const float* xb = x + (size_t)b * (N_NODE * T_LEN);
    int sap = length[b] / STRIDE_;
    int tvalid = sap * STRIDE_;

    // init persistent window-max
    float* wmax = (float*)&smem[WMOFF];
    #pragma unroll
    for (int i = 0; i < 7; ++i) wmax[tid + i * 256] = 0.f;

    for (int ti = 0; ti < 3; ++ti) {
        int t0 = ti * 128;
        int tg = t0 + 2 * lane;
        bool tok = tg < T_LEN;
        int xfb = quad * RP + (lm & 1) * 1024 + (lm >> 1) * 16 + wt * 512;

        f32x4 acc[4][4];
        #pragma unroll
        for (int i = 0; i < 4; ++i)
            #pragma unroll
            for (int j = 0; j < 4; ++j) acc[i][j] = (f32x4){0.f, 0.f, 0.f, 0.f};
        float ssq0 = 0.f, ssq1 = 0.f;

        float2 xv[8];
        auto loadX = [&](int s) {
            int kb = s * 32 + wid * 8;
            #pragma unroll
            for (int e = 0; e < 8; ++e) {
                int k = kb + e;                       // wave-uniform guard
                xv[e] = (tok && k < N_NODE) ? *(const float2*)(xb + k * T_LEN + tg)
                                            : make_float2(0.f, 0.f);
            }
        };
        auto cw = [&](int buf) {   // truncation split: hi=f&0xFFFF0000, lo exact then trunc
            union { u16 us[8]; uint4 v; } H0, H1, L0, L1;
            #pragma unroll
            for (int e = 0; e < 8; ++e) {
                float f0 = xv[e].x, f1 = xv[e].y;
                ssq0 = fmaf(f0, f0, ssq0); ssq1 = fmaf(f1, f1, ssq1);
                unsigned u0 = __float_as_uint(f0), u1 = __float_as_uint(f1);
                H0.us[e] = (u16)(u0 >> 16);
                H1.us[e] = (u16)(u1 >> 16);
                float l0 = f0 - __uint_as_float(u0 & 0xFFFF0000u);
                float l1 = f1 - __uint_as_float(u1 & 0xFFFF0000u);
                L0.us[e] = (u16)(__float_as_uint(l0) >> 16);
                L1.us[e] = (u16)(__float_as_uint(l1) >> 16);
            }
            char* bp = smem + buf * DBS + wid * RP + lane * 16;
            *(uint4*)(bp)                = H0.v;
            *(uint4*)(bp + 1024)         = H1.v;
            *(uint4*)(bp + XLOFF)        = L0.v;
            *(uint4*)(bp + XLOFF + 1024) = L1.v;
        };

        loadX(0); cw(0);
        bf16x8 ah[4], al[4], xh[4], xl[4];
        for (int s = 0; s < 7; ++s) {
            const u16* Ab  = AhF + (size_t)(s * 8 + pbq) * 2048 + lane * 8;
            const u16* Ab2 = AlF + (size_t)(s * 8 + pbq) * 2048 + lane * 8;
            #pragma unroll
            for (int i = 0; i < 4; ++i) {
                ah[i] = *(const bf16x8*)(Ab  + i * 512);
                al[i] = *(const bf16x8*)(Ab2 + i * 512);
            }
            if (s < 6) loadX(s + 1);
            __syncthreads();
            const char* rb = smem + (s & 1) * DBS + xfb;
            #pragma unroll
            for (int j = 0; j < 4; ++j) {
                xh[j] = *(const bf16x8*)(rb + j * 128);
                xl[j] = *(const bf16x8*)(rb + XLOFF + j * 128);
            }
            #pragma unroll
            for (int i = 0; i < 4; ++i)
                #pragma unroll
                for (int j = 0; j < 4; ++j)
                    acc[i][j] = __builtin_amdgcn_mfma_f32_16x16x32_bf16(ah[i], xh[j], acc[i][j], 0, 0, 0);
            #pragma unroll
            for (int i = 0; i < 4; ++i)
                #pragma unroll
                for (int j = 0; j < 4; ++j)
                    acc[i][j] = __builtin_amdgcn_mfma_f32_16x16x32_bf16(ah[i], xl[j], acc[i][j], 0, 0, 0);
            #pragma unroll
            for (int i = 0; i < 4; ++i)
                #pragma unroll
                for (int j = 0; j < 4; ++j)
                    acc[i][j] = __builtin_amdgcn_mfma_f32_16x16x32_bf16(al[i], xh[j], acc[i][j], 0, 0, 0);
            if (s < 6) cw((s + 1) & 1);
        }

        // frame-norm for this t-tile
        __syncthreads();
        *(float2*)&smem[SQOFF + tid * 8] = make_float2(ssq0, ssq1);
        __syncthreads();
        if (tid < 64) {
            float a0 = 0.f, a1 = 0.f;
            #pragma unroll
            for (int w2 = 0; w2 < 4; ++w2) {
                float2 v = *(float2*)&smem[SQOFF + (w2 * 64 + tid) * 8];
                a0 += v.x; a1 += v.y;
            }
            float rs = 1.0f / (float)sap;
            int ta = t0 + 2 * tid;
            ((float*)&smem[IVOFF])[2 * tid]     = (ta     < tvalid) ? rs / sqrtf(a0 + 1e-9f) : 0.f;
            ((float*)&smem[IVOFF])[2 * tid + 1] = (ta + 1 < tvalid) ? rs / sqrtf(a1 + 1e-9f) : 0.f;
        }
        __syncthreads();
        float invv[4];
        #pragma unroll
        for (int j = 0; j < 4; ++j) invv[j] = ((float*)&smem[IVOFF])[wt * 64 + j * 16 + lm];

        // epilogue: 4 rounds x 32 p-rows, pooled into persistent wmax (no atomics)
        float* Ss = (float*)smem;             // aliases dead X buffers
        int wbase = t0 / STRIDE_;
        int tmax = min(t0 + 128, T_POOL);
        for (int rr = 0; rr < 4; ++rr) {
            __syncthreads();
            if (wp == (rr >> 1)) {
                #pragma unroll
                for (int i2 = 0; i2 < 2; ++i2) {
                    int i = (rr & 1) * 2 + i2;
                    #pragma unroll
                    for (int j = 0; j < 4; ++j) {
                        int col = wt * 64 + j * 16 + lm;
                        #pragma unroll
                        for (int r = 0; r < 4; ++r)
                            Ss[(i2 * 16 + quad * 4 + r) * 132 + col] = acc[i][j][r] * invv[j];
                    }
                }
            }
            __syncthreads();
            int sidx = tid & 7, pl = tid >> 3;        // 32 rows x 8 windows
            int w = wbase + sidx;
            int tlo = max(w * STRIDE_, t0), thi = min(w * STRIDE_ + STRIDE_, tmax);
            if (w < NWIN && tlo < thi) {
                float m = -3.4e38f;
                for (int t = tlo; t < thi; ++t) m = fmaxf(m, Ss[pl * 132 + (t - t0)]);
                int row = rr * 32 + pl;
                wmax[row * 14 + w] = fmaxf(wmax[row * 14 + w], m);
            }
        }
        __syncthreads();   // Ss reads done before next t-iter restages buf0
    }

    // flush wmax -> pos (plain stores; this block owns [b][p0..p0+128))
    float* posb = pos + ((size_t)b * P_PAD + p0) * NWIN;
    #pragma unroll
    for (int i = 0; i < 7; ++i) posb[tid + i * 256] = wmax[tid + i * 256];
    __syncthreads();                     // drains vmem before fence/atomic

    // last-arrival gate for batch b
    volatile int* flagp = (volatile int*)smem;
    if (tid == 0) {
        __threadfence();
        unsigned old = atomicAdd(&ctr[b], 1u);
        *flagp = (old == 3u) ? 1 : 0;
    }
    __syncthreads();
    int flag = *flagp;
    __syncthreads();                     // everyone has read flag before smem reuse
    if (!flag) return;
    __threadfence();                     // acquire: see other blocks' pos writes

    // ---- classifier + norm for this b ----
    float* cf0 = (float*)smem;           // [400]
    float* cf1 = (float*)(smem + 1600);  // [400]
    float* sh  = (float*)(smem + 3200);  // [512]
    for (int p = tid; p < P_PAT; p += 256) {
        int tn[3]; float tv[3];
        #pragma unroll
        for (int i = 0; i < 3; ++i) { tn[i] = topn_w[p * 3 + i]; tv[i] = topv_w[p * 3 + i]; }
        float c0 = 0.f, c1 = 0.f;
        #pragma unroll
        for (int i = 0; i < 3; ++i)
            #pragma unroll
            for (int j = 0; j < 3; ++j) {
                int nm = tn[i] * N_NODE + tn[j];
                float f = tv[i] * tv[j] / ((float)mg[nm] + 1e-9f);
                c0 += f * W[nm * 2 + 0];
                c1 += f * W[nm * 2 + 1];
            }
        cf0[p] = c0; cf1[p] = c1;
    }
    __syncthreads();
    float s0 = 0.f, s1 = 0.f;
    for (int p = tid; p < P_PAT; p += 256) {
        const float* pp = pos + ((size_t)b * P_PAD + p) * NWIN;
        float fs = 0.f;
        #pragma unroll
        for (int w = 0; w < NWIN; ++w) fs += pp[w];
        s0 += fs * cf0[p];
        s1 += fs * cf1[p];
    }
    sh[tid] = s0; sh[256 + tid] = s1;
    __syncthreads();
    for (int o = 128; o > 0; o >>= 1) {
        if (tid < o) { sh[tid] += sh[tid + o]; sh[256 + tid] += sh[256 + tid + o]; }
        __syncthreads();
    }
    if (tid == 0) {
        out[b * 2 + 0] = sh[0]   + bcls[0];
        out[b * 2 + 1] = sh[256] + bcls[1];
    }
    if (b == 0) {
        __syncthreads();
        float ns = 0.f;
        for (int i = tid; i < P_PAT; i += 256) ns += normt[i];
        sh[tid] = ns;
        __syncthreads();
        for (int o = 128; o > 0; o >>= 1) {
            if (tid < o) sh[tid] += sh[tid + o];
            __syncthreads();
        }
        if (tid == 0) { out[256] = sh[0]; out[257] = 0.f; }
    }
}

extern "C" void kernel_launch(void* const* d_in, const int* in_sizes, int n_in,
                              void* d_out, int out_size, void* d_ws, size_t ws_size,
                              hipStream_t stream) {
    (void)in_sizes; (void)n_in; (void)out_size; (void)ws_size;
    const float* x        = (const float*)d_in[0];
    const int*   length   = (const int*)d_in[1];
    const float* patterns = (const float*)d_in[2];
    const float* Wcls     = (const float*)d_in[3];
    const float* bcls     = (const float*)d_in[4];
    float* out = (float*)d_out;
    char* ws = (char*)d_ws;

    u16*      Ah    = (u16*)(ws + O_AH);
    u16*      Al    = (u16*)(ws + O_AL);
    int*      mg    = (int*)(ws + O_MG);
    unsigned* ctr   = (unsigned*)(ws + O_CTR);
    float*    pos   = (float*)(ws + O_POS);
    int*      topn  = (int*)(ws + O_TOPN);
    float*    topv  = (float*)(ws + O_TOPV);
    float*    normt = (float*)(ws + O_NORMT);

    hipMemsetAsync(mg, 0, 160512, stream);              // mg + ctr, one node
    k_pat<<<P_PAD, 64, 0, stream>>>(patterns, Ah, Al, mg, topn, topv, normt);
    k_gemm<<<512, 256, 0, stream>>>(x, Ah, Al, length, pos, ctr,
                                    topn, topv, mg, Wcls, normt, bcls, out);
}

// Round 7
// 138.357 us; speedup vs baseline: 2.2280x; 2.2280x over previous
//
#include <hip/hip_runtime.h>

#define N_NODE 200
#define T_LEN 360
#define T_POOL 350
#define P_PAT 400
#define P_PAD 512
#define NWIN 14
#define STRIDE_ 25
#define KPAD 224            // 7 stages x 32

// ---- workspace layout (bytes) ----
#define O_AH    0           // A hi, MFMA-fragment order: [7][8][4][64][8] bf16 = 229376
#define O_POS   229376      // [128][512][14] u32 = 3670016 (zeroed by k_pat, fkey atomicMax)
#define O_TOPN  3899392     // [400][3] i32
#define O_TOPV  3904192     // [400][3] f32
#define O_NORMT 3908992     // [400] f32

typedef unsigned short u16;
typedef __attribute__((ext_vector_type(8))) short bf16x8;
typedef __attribute__((ext_vector_type(4))) float f32x4;

// LDS layout (bytes) for k_gemm: single-plane X double-buffer
#define RP 2064             // X row pitch (4 k-oct rows; even-t [0,1024), odd-t [1024,2048))
#define DBS 8256            // one buffer (4*RP)
#define SQOFF 16512         // ssq scratch 256*8
#define IVOFF 18560         // inv-norm per local t (128 f32)
#define SMEM_BYTES 19072    // Ss (16*132*4=8448) aliases dead X buffers at [0,8448)

__device__ __forceinline__ unsigned fkey(float f) {
    unsigned u = __float_as_uint(f);
    return (u & 0x80000000u) ? ~u : (u | 0x80000000u);
}
__device__ __forceinline__ u16 f2bf(float f) {          // RNE (A-side prep)
    unsigned u = __float_as_uint(f);
    unsigned r = u + 0x7FFFu + ((u >> 16) & 1u);
    return (u16)(r >> 16);
}

// ---- pattern prep: normalize, top-3, norm term, frag-order bf16 A, pos zero ----
__global__ void k_pat(const float* __restrict__ pat, u16* __restrict__ Ah,
                      int* __restrict__ topn_w, float* __restrict__ topv_w,
                      float* __restrict__ normt, unsigned* __restrict__ pos)
{
    int p = blockIdx.x;               // 0..511
    int lane = threadIdx.x;
    bool pv = p < P_PAT;

    {   // zero pos: 917504 u32 = 512 blocks x 64 threads x 28
        int base = blockIdx.x * 64 + lane;
        #pragma unroll
        for (int i = 0; i < 28; ++i) pos[base + i * 32768] = 0u;
    }

    float sv[4], av[4];
    int nn[4];
    float ss = 0.f;
    #pragma unroll
    for (int j = 0; j < 4; ++j) {
        int n = lane + 64 * j;
        nn[j] = n;
        if (pv && n < N_NODE) { float v = pat[p * N_NODE + n]; sv[j] = v; av[j] = fabsf(v); ss += v * v; }
        else { sv[j] = 0.f; av[j] = -1.f; }
    }
    #pragma unroll
    for (int off = 32; off >= 1; off >>= 1) ss += __shfl_xor(ss, off);
    float rn = 1.0f / sqrtf(ss + 1e-9f);

    // fragment-order A (hi only): idx = (((s*8+pb)*4+i)*64 + quad*16+plm)*8 + e
    int pb = p >> 6, ii = (p >> 4) & 3, plm = p & 15;
    #pragma unroll
    for (int j = 0; j < 4; ++j) {
        int n = nn[j];
        if (n < KPAD) {
            float v = (pv && n < N_NODE) ? sv[j] * rn : 0.f;
            int s = n >> 5, c = n & 31, quad = c >> 3, e = c & 7;
            size_t idx = ((size_t)((s * 8 + pb) * 4 + ii) * 64 + quad * 16 + plm) * 8 + e;
            Ah[idx] = f2bf(v);
        }
    }
    if (!pv) return;

    int topn[3]; float topv[3];
    for (int r = 0; r < 3; ++r) {
        float bv = -2.f; int bi = 1 << 30;
        #pragma unroll
        for (int j = 0; j < 4; ++j)
            if (av[j] > bv || (av[j] == bv && nn[j] < bi)) { bv = av[j]; bi = nn[j]; }
        #pragma unroll
        for (int off = 32; off >= 1; off >>= 1) {
            float ov = __shfl_xor(bv, off); int oi = __shfl_xor(bi, off);
            if (ov > bv || (ov == bv && oi < bi)) { bv = ov; bi = oi; }
        }
        int jj = bi >> 6, src = bi & 63;
        float rawj = (jj == 0) ? sv[0] : (jj == 1) ? sv[1] : (jj == 2) ? sv[2] : sv[3];
        float raw = __shfl(rawj, src);
        topn[r] = bi; topv[r] = raw * rn;
        #pragma unroll
        for (int j = 0; j < 4; ++j) if (nn[j] == bi) av[j] = -1.f;
    }
    float fullnorm = sqrtf(ss) * rn;
    float topnorm = sqrtf(topv[0]*topv[0] + topv[1]*topv[1] + topv[2]*topv[2]);
    if (lane == 0) {
        float d = 1.0f - topnorm / fullnorm;
        normt[p] = d * d * (1.0f / 800.0f);
    }
    if (lane < 3) { topn_w[p * 3 + lane] = topn[lane]; topv_w[p * 3 + lane] = topv[lane]; }
}

// ---- MFMA GEMM (1-term bf16) + inline frame-norm + windowed max (R4 structure) ----
__global__ __launch_bounds__(256, 3) void k_gemm(const float* __restrict__ x,
    const u16* __restrict__ AhF, const int* __restrict__ length,
    unsigned* __restrict__ pos)
{
    __shared__ __align__(16) char smem[SMEM_BYTES];
    int tid = threadIdx.x;
    int b = blockIdx.z, p0 = blockIdx.y * 128, t0 = blockIdx.x * 128;
    int lane = tid & 63, wid = tid >> 6;
    int quad = lane >> 4, lm = lane & 15;
    int wp = wid >> 1, wt = wid & 1;
    int pbq = blockIdx.y * 2 + wp;
    const float* xb = x + (size_t)b * (N_NODE * T_LEN);

    f32x4 acc[4][4];
    #pragma unroll
    for (int i = 0; i < 4; ++i)
        #pragma unroll
        for (int j = 0; j < 4; ++j) acc[i][j] = (f32x4){0.f, 0.f, 0.f, 0.f};
    float ssq0 = 0.f, ssq1 = 0.f;

    int tg = t0 + 2 * lane;
    bool tok = tg < T_LEN;
    int xfb = quad * RP + (lm & 1) * 1024 + (lm >> 1) * 16 + wt * 512;

    float2 xv[8];
    auto loadX = [&](int s) {
        int kb = s * 32 + wid * 8;
        #pragma unroll
        for (int e = 0; e < 8; ++e) {
            int k = kb + e;                       // wave-uniform guard
            xv[e] = (tok && k < N_NODE) ? *(const float2*)(xb + k * T_LEN + tg)
                                        : make_float2(0.f, 0.f);
        }
    };
    auto cw = [&](int buf) {   // truncation f32->bf16 (hi only), accumulate exact ssq
        union { u16 us[8]; uint4 v; } H0, H1;
        #pragma unroll
        for (int e = 0; e < 8; ++e) {
            float f0 = xv[e].x, f1 = xv[e].y;
            ssq0 = fmaf(f0, f0, ssq0); ssq1 = fmaf(f1, f1, ssq1);
            H0.us[e] = (u16)(__float_as_uint(f0) >> 16);
            H1.us[e] = (u16)(__float_as_uint(f1) >> 16);
        }
        char* bp = smem + buf * DBS + wid * RP + lane * 16;
        *(uint4*)(bp)        = H0.v;   // even t
        *(uint4*)(bp + 1024) = H1.v;   // odd t
    };

    loadX(0); cw(0);
    bf16x8 ah[4], xh[4];
    for (int s = 0; s < 7; ++s) {
        const u16* Ab = AhF + (size_t)(s * 8 + pbq) * 2048 + lane * 8;
        #pragma unroll
        for (int i = 0; i < 4; ++i) ah[i] = *(const bf16x8*)(Ab + i * 512);
        if (s < 6) loadX(s + 1);
        __syncthreads();
        const char* rb = smem + (s & 1) * DBS + xfb;
        #pragma unroll
        for (int j = 0; j < 4; ++j) xh[j] = *(const bf16x8*)(rb + j * 128);
        #pragma unroll
        for (int i = 0; i < 4; ++i)
            #pragma unroll
            for (int j = 0; j < 4; ++j)
                acc[i][j] = __builtin_amdgcn_mfma_f32_16x16x32_bf16(ah[i], xh[j], acc[i][j], 0, 0, 0);
        if (s < 6) cw((s + 1) & 1);
    }

    // frame-norm (validity + 1/sap folded)
    *(float2*)&smem[SQOFF + tid * 8] = make_float2(ssq0, ssq1);
    __syncthreads();
    int sap = length[b] / STRIDE_;
    int tvalid = sap * STRIDE_;
    if (tid < 64) {
        float a0 = 0.f, a1 = 0.f;
        #pragma unroll
        for (int w2 = 0; w2 < 4; ++w2) {
            float2 v = *(float2*)&smem[SQOFF + (w2 * 64 + tid) * 8];
            a0 += v.x; a1 += v.y;
        }
        float rs = 1.0f / (float)sap;
        int ta = t0 + 2 * tid;
        ((float*)&smem[IVOFF])[2 * tid]     = (ta     < tvalid) ? rs / sqrtf(a0 + 1e-9f) : 0.f;
        ((float*)&smem[IVOFF])[2 * tid + 1] = (ta + 1 < tvalid) ? rs / sqrtf(a1 + 1e-9f) : 0.f;
    }
    __syncthreads();
    float invv[4];
    #pragma unroll
    for (int j = 0; j < 4; ++j) invv[j] = ((float*)&smem[IVOFF])[wt * 64 + j * 16 + lm];

    // epilogue: 4 rounds x 32 p-rows (Ss aliases dead X buffers)
    float* Ss = (float*)smem;
    int wbase = t0 / STRIDE_;
    int tmax = min(t0 + 128, T_POOL);
    for (int rr = 0; rr < 4; ++rr) {
        __syncthreads();
        if (wp == (rr >> 1)) {
            #pragma unroll
            for (int i2 = 0; i2 < 2; ++i2) {
                int i = (rr & 1) * 2 + i2;
                #pragma unroll
                for (int j = 0; j < 4; ++j) {
                    int col = wt * 64 + j * 16 + lm;
                    #pragma unroll
                    for (int r = 0; r < 4; ++r)
                        Ss[(i2 * 16 + quad * 4 + r) * 132 + col] = acc[i][j][r] * invv[j];
                }
            }
        }
        __syncthreads();
        int sidx = tid & 7, pl = tid >> 3;
        int w = wbase + sidx;
        int tlo = max(w * STRIDE_, t0), thi = min(w * STRIDE_ + STRIDE_, tmax);
        if (w < NWIN && tlo < thi) {
            float m = -3.4e38f;
            for (int t = tlo; t < thi; ++t) m = fmaxf(m, Ss[pl * 132 + (t - t0)]);
            atomicMax(&pos[((size_t)b * P_PAD + p0 + rr * 32 + pl) * NWIN + w], fkey(m));
        }
    }
}

// ---- final: maskgraph on-the-fly (bitmask popcount), coef, fs reduce, norm reduce ----
__global__ void k_out(const unsigned* __restrict__ pos, const int* __restrict__ topn_w,
                      const float* __restrict__ topv_w, const float* __restrict__ W,
                      const float* __restrict__ normt, const float* __restrict__ bcls,
                      float* __restrict__ out)
{
    __shared__ unsigned maskT[N_NODE * 13];   // bit q of node n: maskT[n*13 + (q>>5)]
    __shared__ float cf0[P_PAT], cf1[P_PAT];
    __shared__ float sh[512];
    int b = blockIdx.x, tid = threadIdx.x;

    for (int i = tid; i < N_NODE * 13; i += 256) maskT[i] = 0u;
    __syncthreads();
    for (int idx = tid; idx < P_PAT * 3; idx += 256) {
        int q = idx / 3;
        int n = topn_w[idx];
        atomicOr(&maskT[n * 13 + (q >> 5)], 1u << (q & 31));
    }
    __syncthreads();

    for (int p = tid; p < P_PAT; p += 256) {
        int tn[3]; float tv[3];
        #pragma unroll
        for (int i = 0; i < 3; ++i) { tn[i] = topn_w[p * 3 + i]; tv[i] = topv_w[p * 3 + i]; }
        float c0 = 0.f, c1 = 0.f;
        #pragma unroll
        for (int i = 0; i < 3; ++i)
            #pragma unroll
            for (int j = 0; j < 3; ++j) {
                int a = tn[i], bb = tn[j];
                int mgv = 0;
                #pragma unroll
                for (int w = 0; w < 13; ++w)
                    mgv += __popc(maskT[a * 13 + w] & maskT[bb * 13 + w]);
                int nm = a * N_NODE + bb;
                float f = tv[i] * tv[j] / ((float)mgv + 1e-9f);
                c0 += f * W[nm * 2 + 0];
                c1 += f * W[nm * 2 + 1];
            }
        cf0[p] = c0; cf1[p] = c1;
    }
    __syncthreads();
    float s0 = 0.f, s1 = 0.f;
    for (int p = tid; p < P_PAT; p += 256) {
        const unsigned* pp = pos + ((size_t)b * P_PAD + p) * NWIN;
        float fs = 0.f;
        #pragma unroll
        for (int w = 0; w < NWIN; ++w) {
            unsigned k = pp[w];
            unsigned u = (k & 0x80000000u) ? (k ^ 0x80000000u) : ~k;
            fs += __uint_as_float(u);
        }
        s0 += fs * cf0[p];
        s1 += fs * cf1[p];
    }
    sh[tid] = s0; sh[256 + tid] = s1;
    __syncthreads();
    for (int o = 128; o > 0; o >>= 1) {
        if (tid < o) { sh[tid] += sh[tid + o]; sh[256 + tid] += sh[256 + tid + o]; }
        __syncthreads();
    }
    if (tid == 0) {
        out[b * 2 + 0] = sh[0]   + bcls[0];
        out[b * 2 + 1] = sh[256] + bcls[1];
    }
    if (b == 0) {
        __syncthreads();
        float ns = 0.f;
        for (int i = tid; i < P_PAT; i += 256) ns += normt[i];
        sh[tid] = ns;
        __syncthreads();
        for (int o = 128; o > 0; o >>= 1) {
            if (tid < o) sh[tid] += sh[tid + o];
            __syncthreads();
        }
        if (tid == 0) { out[256] = sh[0]; out[257] = 0.f; }
    }
}

extern "C" void kernel_launch(void* const* d_in, const int* in_sizes, int n_in,
                              void* d_out, int out_size, void* d_ws, size_t ws_size,
                              hipStream_t stream) {
    (void)in_sizes; (void)n_in; (void)out_size; (void)ws_size;
    const float* x        = (const float*)d_in[0];
    const int*   length   = (const int*)d_in[1];
    const float* patterns = (const float*)d_in[2];
    const float* Wcls     = (const float*)d_in[3];
    const float* bcls     = (const float*)d_in[4];
    float* out = (float*)d_out;
    char* ws = (char*)d_ws;

    u16*      Ah    = (u16*)(ws + O_AH);
    unsigned* pos   = (unsigned*)(ws + O_POS);
    int*      topn  = (int*)(ws + O_TOPN);
    float*    topv  = (float*)(ws + O_TOPV);
    float*    normt = (float*)(ws + O_NORMT);

    k_pat<<<P_PAD, 64, 0, stream>>>(patterns, Ah, topn, topv, normt, pos);
    k_gemm<<<dim3(3, 4, 128), 256, 0, stream>>>(x, Ah, length, pos);
    k_out<<<128, 256, 0, stream>>>(pos, topn, topv, Wcls, normt, bcls, out);
}